// Round 3
// baseline (81.623 us; speedup 1.0000x reference)
//
#include <hip/hip_runtime.h>
#include <hip/hip_bf16.h>
#include <math.h>

#define N_CELLS 65536
#define NH 7
#define NV 4
#define E_IN 16
#define E_OUT 16
#define N_OFF 4
#define N_SIG 4
#define NB 2
#define NK 16            // N_OFF * N_SIG

#define CPB 32           // cells per block
#define THREADS 256
#define PAIRS 4          // cell-pairs per wave

typedef __attribute__((ext_vector_type(8))) short bf16x8;
typedef __attribute__((ext_vector_type(4))) float f32x4;

static __device__ __forceinline__ short f2bf(float f) {
    union { float f; unsigned u; } a; a.f = f;
    unsigned u = a.u;
    u += 0x7fff + ((u >> 16) & 1);   // round-nearest-even
    return (short)(u >> 16);
}

__global__ __launch_bounds__(THREADS, 2) void mge_kernel(
    const float* __restrict__ x,
    const float* __restrict__ coords,
    const float* __restrict__ sigma,
    const float* __restrict__ dist_offsets,
    const float* __restrict__ W,
    const float* __restrict__ b_out,
    const int*   __restrict__ adjc,
    const int*   __restrict__ nh_mask,
    float* __restrict__ out)
{
    // W pre-packed into per-lane MFMA fragment layout: [st][grp][col][j] bf16
    __shared__ short wf_lds[8 * 4 * 16 * 8];       // 8 KB
    __shared__ float nd_lds[CPB][NK][8];           // padded to 8 -> 16 KB, 32B-aligned rows
    __shared__ int   adj_lds[CPB][NH];
    __shared__ float d_lds[CPB][NH];
    __shared__ float m_lds[CPB][NH];

    const int t = threadIdx.x;
    const int base = blockIdx.x * CPB;

    // ---- stage W: coalesced float4 read, convert, scatter to fragment layout ----
    {
        const float4* src = (const float4*)W;
        #pragma unroll
        for (int i = 0; i < 4; ++i) {
            const int idx4 = i * THREADS + t;      // float4 index into W
            const float4 q = src[idx4];
            const int flat = idx4 * 4;             // flat = kk*16 + col
            const int col0 = flat & 15;            // col of q.x (col0..col0+3 contiguous)
            const int kk   = flat >> 4;
            const int j    = kk & 7;
            const int grp  = (kk >> 3) & 3;
            const int st   = kk >> 5;
            short* dst = &wf_lds[(((st * 4 + grp) * 16) + col0) * 8 + j];
            dst[0 * 8] = f2bf(q.x);
            dst[1 * 8] = f2bf(q.y);
            dst[2 * 8] = f2bf(q.z);
            dst[3 * 8] = f2bf(q.w);
        }
    }

    // ---- distances: 32 cells x 7 neighbors = 224 tasks ----
    if (t < CPB * NH) {
        const int cl = t / NH;
        const int h  = t % NH;
        const int n  = base + cl;
        const int a  = adjc[n * NH + h];
        const int m  = nh_mask[n * NH + h];
        adj_lds[cl][h] = a;
        const float lat_c = coords[n];
        const float lon_c = coords[N_CELLS + n];
        const float lat_n = coords[a];
        const float lon_n = coords[N_CELLS + a];
        float cosd = sinf(lat_c) * sinf(lat_n) +
                     cosf(lat_c) * cosf(lat_n) * cosf(lon_n - lon_c);
        cosd = fminf(fmaxf(cosd, -1.0f + 1e-7f), 1.0f - 1e-7f);
        d_lds[cl][h] = acosf(cosd);
        m_lds[cl][h] = (float)m;
    }
    __syncthreads();

    // ---- nd weights: 32 cells x 16 (o,s) = 512 tasks, 2/thread ----
    #pragma unroll
    for (int it = 0; it < 2; ++it) {
        const int task = it * THREADS + t;
        const int cl = task >> 4;
        const int k  = task & 15;          // k = o*N_SIG + s
        const int o  = k >> 2;
        const int s  = k & 3;
        const float off     = dist_offsets[o];
        const float inv_sig = 1.0f / sigma[s];
        float raw[NH];
        float sum = 0.0f;
        #pragma unroll
        for (int h = 0; h < NH; ++h) {
            const float df = (d_lds[cl][h] - off) * inv_sig;
            const float e  = __expf(-0.5f * df * df) * m_lds[cl][h];
            raw[h] = e;
            sum += e;
        }
        const float inv = 1.0f / (sum + 1e-8f);
        #pragma unroll
        for (int h = 0; h < NH; ++h)
            nd_lds[cl][k][h] = raw[h] * inv;
        nd_lds[cl][k][7] = 0.0f;           // pad slot
    }

    // ---- per-lane B fragments: 8 conflict-free ds_read_b128 ----
    const int lane = t & 63;
    const int wv   = t >> 6;
    const int col  = lane & 15;
    const int grp  = lane >> 4;

    bf16x8 bfrag[8];
    #pragma unroll
    for (int st = 0; st < 8; ++st)
        bfrag[st] = *(const bf16x8*)&wf_lds[((st * 4 + grp) * 16 + col) * 8];
    const float bias = b_out[col];
    __syncthreads();

    // ---- main: 2 cells per MFMA tile, 4 pairs per wave ----
    const int cl_in_pair = (lane & 15) >> 3;
    const int bv = lane & 7;
    const int b  = bv >> 2;
    const int v  = bv & 3;
    const int e0 = (grp & 1) * 8;
    const int kos_off = grp >> 1;

    #pragma unroll 1
    for (int p = 0; p < PAIRS; ++p) {
        const int c0 = wv * 8 + p * 2;
        const int cl = c0 + cl_in_pair;

        float xr[NH][8];
        #pragma unroll
        for (int h = 0; h < NH; ++h) {
            const int a = adj_lds[cl][h];
            const float4* px = (const float4*)(x + ((((size_t)b * N_CELLS + a) * NV + v) << 4) + e0);
            const float4 q0 = px[0], q1 = px[1];
            xr[h][0] = q0.x; xr[h][1] = q0.y; xr[h][2] = q0.z; xr[h][3] = q0.w;
            xr[h][4] = q1.x; xr[h][5] = q1.y; xr[h][6] = q1.z; xr[h][7] = q1.w;
        }

        f32x4 acc = {0.f, 0.f, 0.f, 0.f};
        #pragma unroll
        for (int st = 0; st < 8; ++st) {
            const int k2 = st * 2 + kos_off;
            const float4 n0 = *(const float4*)&nd_lds[cl][k2][0];
            const float4 n1 = *(const float4*)&nd_lds[cl][k2][4];
            const float nds[NH] = {n0.x, n0.y, n0.z, n0.w, n1.x, n1.y, n1.z};

            bf16x8 aa;
            #pragma unroll
            for (int j = 0; j < 8; ++j) {
                float s = 0.0f;
                #pragma unroll
                for (int h = 0; h < NH; ++h) s += nds[h] * xr[h][j];
                aa[j] = f2bf(s);
            }
            acc = __builtin_amdgcn_mfma_f32_16x16x32_bf16(aa, bfrag[st], acc, 0, 0, 0);
        }

        // store: D col = lane&15, row = grp*4 + r
        #pragma unroll
        for (int r = 0; r < 4; ++r) {
            const int rr  = grp * 4 + r;
            const int cs  = rr >> 3;
            const int bvs = rr & 7;
            const int bs  = bvs >> 2;
            const int vs  = bvs & 3;
            const int cell = base + c0 + cs;
            out[((((size_t)bs * N_CELLS + cell) * NV + vs) << 4) + col] = acc[r] + bias;
        }
    }
}

extern "C" void kernel_launch(void* const* d_in, const int* in_sizes, int n_in,
                              void* d_out, int out_size, void* d_ws, size_t ws_size,
                              hipStream_t stream) {
    const float* x            = (const float*)d_in[0];
    const float* coords       = (const float*)d_in[1];
    const float* sigma        = (const float*)d_in[2];
    const float* dist_offsets = (const float*)d_in[3];
    const float* W            = (const float*)d_in[4];
    const float* b_out        = (const float*)d_in[5];
    const int*   adjc         = (const int*)d_in[6];
    const int*   nh_mask     = (const int*)d_in[7];
    float* out = (float*)d_out;

    dim3 grid(N_CELLS / CPB);
    mge_kernel<<<grid, THREADS, 0, stream>>>(x, coords, sigma, dist_offsets, W,
                                             b_out, adjc, nh_mask, out);
}

// Round 4
// 76.911 us; speedup vs baseline: 1.0613x; 1.0613x over previous
//
#include <hip/hip_runtime.h>
#include <hip/hip_bf16.h>
#include <math.h>

#define N_CELLS 65536
#define NH 7
#define NV 4
#define E_IN 16
#define E_OUT 16
#define N_OFF 4
#define N_SIG 4
#define NK 16            // N_OFF * N_SIG

#define CPB 32           // cells per block
#define THREADS 256

typedef __attribute__((ext_vector_type(8))) short bf16x8;
typedef __attribute__((ext_vector_type(4))) float f32x4;

static __device__ __forceinline__ short f2bfs(float f) {
    __hip_bfloat16 h = __float2bfloat16(f);
    short s;
    __builtin_memcpy(&s, &h, 2);
    return s;
}

// ---- one-time: pack W into per-lane MFMA B-fragment layout [st][grp][col][j] (bf16)
__global__ void pack_w_kernel(const float* __restrict__ W, short* __restrict__ wf) {
    const int kk  = threadIdx.x;       // flat K index = k_os*16 + e, 0..255
    const int j   = kk & 7;
    const int grp = (kk >> 3) & 3;
    const int st  = kk >> 5;
    #pragma unroll
    for (int col = 0; col < E_OUT; ++col)
        wf[(((st * 4 + grp) * 16) + col) * 8 + j] = f2bfs(W[kk * E_OUT + col]);
}

__global__ __launch_bounds__(THREADS, 3) void mge_kernel(
    const float* __restrict__ x,
    const float* __restrict__ coords,
    const float* __restrict__ sigma,
    const float* __restrict__ dist_offsets,
    const short* __restrict__ wf,      // packed W fragments in d_ws
    const float* __restrict__ b_out,
    const int*   __restrict__ adjc,
    const int*   __restrict__ nh_mask,
    float* __restrict__ out)
{
    __shared__ float nd_lds[CPB][NK][8];   // padded rows (32B) -> 16 KB
    __shared__ int   adj_lds[CPB][NH];
    __shared__ float d_lds[CPB][NH];
    __shared__ float m_lds[CPB][NH];

    const int t = threadIdx.x;
    const int base = blockIdx.x * CPB;

    // ---- distances: 32 cells x 7 neighbors = 224 tasks ----
    if (t < CPB * NH) {
        const int cl = t / NH;
        const int h  = t % NH;
        const int n  = base + cl;
        const int a  = adjc[n * NH + h];
        const int m  = nh_mask[n * NH + h];
        adj_lds[cl][h] = a;
        const float lat_c = coords[n];
        const float lon_c = coords[N_CELLS + n];
        const float lat_n = coords[a];
        const float lon_n = coords[N_CELLS + a];
        float cosd = sinf(lat_c) * sinf(lat_n) +
                     cosf(lat_c) * cosf(lat_n) * cosf(lon_n - lon_c);
        cosd = fminf(fmaxf(cosd, -1.0f + 1e-7f), 1.0f - 1e-7f);
        d_lds[cl][h] = acosf(cosd);
        m_lds[cl][h] = (float)m;
    }

    // ---- per-lane B fragments from packed global (L2-hot, coalesced) ----
    const int lane = t & 63;
    const int wv   = t >> 6;
    const int col  = lane & 15;
    const int grp  = lane >> 4;

    bf16x8 bfrag[8];
    #pragma unroll
    for (int st = 0; st < 8; ++st)
        bfrag[st] = ((const bf16x8*)wf)[(st * 4 + grp) * 16 + col];
    const float bias = b_out[col];

    __syncthreads();

    // ---- nd weights: 32 cells x 16 (o,s) = 512 tasks, 2/thread ----
    #pragma unroll
    for (int it = 0; it < 2; ++it) {
        const int task = it * THREADS + t;
        const int cl = task >> 4;
        const int k  = task & 15;          // k = o*N_SIG + s
        const int o  = k >> 2;
        const int s  = k & 3;
        const float off     = dist_offsets[o];
        const float inv_sig = 1.0f / sigma[s];
        float raw[NH];
        float sum = 0.0f;
        #pragma unroll
        for (int h = 0; h < NH; ++h) {
            const float df = (d_lds[cl][h] - off) * inv_sig;
            const float e  = __expf(-0.5f * df * df) * m_lds[cl][h];
            raw[h] = e;
            sum += e;
        }
        const float inv = 1.0f / (sum + 1e-8f);
        #pragma unroll
        for (int h = 0; h < NH; ++h)
            nd_lds[cl][k][h] = raw[h] * inv;
        nd_lds[cl][k][7] = 0.0f;           // pad slot
    }
    __syncthreads();

    // ---- main: 2 cells per MFMA tile, 4 pairs per wave, double-buffered ----
    const int cl_in_pair = (lane & 15) >> 3;
    const int bv = lane & 7;
    const int b  = bv >> 2;
    const int v  = bv & 3;
    const int e0 = (grp & 1) * 8;
    const int kos_off = grp >> 1;

    float xrA[NH][8], xrB[NH][8];

#define LOADXR(XR, PIDX)                                                        \
    {                                                                           \
        const int cl_ = (wv << 3) + ((PIDX) << 1) + cl_in_pair;                 \
        _Pragma("unroll")                                                       \
        for (int h = 0; h < NH; ++h) {                                          \
            const int a = adj_lds[cl_][h];                                      \
            const float4* px = (const float4*)(x +                              \
                ((((size_t)b * N_CELLS + a) * NV + v) << 4) + e0);              \
            const float4 q0 = px[0], q1 = px[1];                                \
            XR[h][0]=q0.x; XR[h][1]=q0.y; XR[h][2]=q0.z; XR[h][3]=q0.w;         \
            XR[h][4]=q1.x; XR[h][5]=q1.y; XR[h][6]=q1.z; XR[h][7]=q1.w;         \
        }                                                                       \
    }

#define COMPUTE(XR, PIDX)                                                       \
    {                                                                           \
        const int c0_ = (wv << 3) + ((PIDX) << 1);                              \
        const int cl_ = c0_ + cl_in_pair;                                       \
        f32x4 acc = {0.f, 0.f, 0.f, 0.f};                                       \
        _Pragma("unroll")                                                       \
        for (int st = 0; st < 8; ++st) {                                        \
            const int k2 = st * 2 + kos_off;                                    \
            const float4 n0 = *(const float4*)&nd_lds[cl_][k2][0];              \
            const float4 n1 = *(const float4*)&nd_lds[cl_][k2][4];              \
            const float nds[NH] = {n0.x, n0.y, n0.z, n0.w, n1.x, n1.y, n1.z};   \
            bf16x8 aa;                                                          \
            _Pragma("unroll")                                                   \
            for (int j = 0; j < 8; ++j) {                                       \
                float s = 0.0f;                                                 \
                _Pragma("unroll")                                               \
                for (int h = 0; h < NH; ++h) s += nds[h] * XR[h][j];            \
                aa[j] = f2bfs(s);                                               \
            }                                                                   \
            acc = __builtin_amdgcn_mfma_f32_16x16x32_bf16(aa, bfrag[st], acc, 0, 0, 0); \
        }                                                                       \
        _Pragma("unroll")                                                       \
        for (int r = 0; r < 4; ++r) {                                           \
            const int rr  = grp * 4 + r;                                        \
            const int cs  = rr >> 3;                                            \
            const int bvs = rr & 7;                                             \
            const int bs  = bvs >> 2;                                           \
            const int vs  = bvs & 3;                                            \
            const int cell = base + c0_ + cs;                                   \
            out[((((size_t)bs * N_CELLS + cell) * NV + vs) << 4) + col] = acc[r] + bias; \
        }                                                                       \
    }

    LOADXR(xrA, 0)
    LOADXR(xrB, 1)          // pair-1 loads in flight during pair-0 compute
    COMPUTE(xrA, 0)
    LOADXR(xrA, 2)
    COMPUTE(xrB, 1)
    LOADXR(xrB, 3)
    COMPUTE(xrA, 2)
    COMPUTE(xrB, 3)

#undef LOADXR
#undef COMPUTE
}

extern "C" void kernel_launch(void* const* d_in, const int* in_sizes, int n_in,
                              void* d_out, int out_size, void* d_ws, size_t ws_size,
                              hipStream_t stream) {
    const float* x            = (const float*)d_in[0];
    const float* coords       = (const float*)d_in[1];
    const float* sigma        = (const float*)d_in[2];
    const float* dist_offsets = (const float*)d_in[3];
    const float* W            = (const float*)d_in[4];
    const float* b_out        = (const float*)d_in[5];
    const int*   adjc         = (const int*)d_in[6];
    const int*   nh_mask      = (const int*)d_in[7];
    float* out = (float*)d_out;
    short* wf  = (short*)d_ws;           // 8 KB packed W fragments

    pack_w_kernel<<<1, 256, 0, stream>>>(W, wf);
    dim3 grid(N_CELLS / CPB);
    mge_kernel<<<grid, THREADS, 0, stream>>>(x, coords, sigma, dist_offsets, wf,
                                             b_out, adjc, nh_mask, out);
}

// Round 5
// 73.033 us; speedup vs baseline: 1.1176x; 1.0531x over previous
//
#include <hip/hip_runtime.h>
#include <hip/hip_bf16.h>
#include <math.h>

#define N_CELLS 65536
#define NH 7
#define NV 4
#define E_IN 16
#define E_OUT 16
#define N_OFF 4
#define N_SIG 4
#define NK 16            // N_OFF * N_SIG

#define CPB 32           // cells per block
#define THREADS 256

typedef __attribute__((ext_vector_type(8))) short bf16x8;
typedef __attribute__((ext_vector_type(4))) float f32x4;

static __device__ __forceinline__ short f2bfs(float f) {
    __hip_bfloat16 h = __float2bfloat16(f);
    short s;
    __builtin_memcpy(&s, &h, 2);
    return s;
}
static __device__ __forceinline__ float b2f(short s) {
    unsigned u = ((unsigned)(unsigned short)s) << 16;
    float f;
    __builtin_memcpy(&f, &u, 4);
    return f;
}

// ---- setup: convert x -> bf16 copy xp (same layout), block 0 also packs W
// into per-lane MFMA B-fragment layout [st][grp][col][j] (bf16).
__global__ __launch_bounds__(256) void setup_kernel(
    const float* __restrict__ x, const float* __restrict__ W,
    short* __restrict__ wf, short* __restrict__ xp)
{
    const int t = threadIdx.x;
    const size_t i = ((size_t)blockIdx.x * 256 + t) * 8;
    const float4* p = (const float4*)(x + i);
    const float4 a = p[0], b = p[1];
    bf16x8 o;
    o[0] = f2bfs(a.x); o[1] = f2bfs(a.y); o[2] = f2bfs(a.z); o[3] = f2bfs(a.w);
    o[4] = f2bfs(b.x); o[5] = f2bfs(b.y); o[6] = f2bfs(b.z); o[7] = f2bfs(b.w);
    *(bf16x8*)(xp + i) = o;

    if (blockIdx.x == 0) {
        const int kk  = t;                 // flat K = k_os*16 + e, 0..255
        const int j   = kk & 7;
        const int grp = (kk >> 3) & 3;
        const int st  = kk >> 5;
        #pragma unroll
        for (int col = 0; col < E_OUT; ++col)
            wf[(((st * 4 + grp) * 16) + col) * 8 + j] = f2bfs(W[kk * E_OUT + col]);
    }
}

__global__ __launch_bounds__(THREADS, 3) void mge_kernel(
    const short* __restrict__ xp,      // bf16 x copy in d_ws
    const float* __restrict__ coords,
    const float* __restrict__ sigma,
    const float* __restrict__ dist_offsets,
    const short* __restrict__ wf,      // packed W fragments in d_ws
    const float* __restrict__ b_out,
    const int*   __restrict__ adjc,
    const int*   __restrict__ nh_mask,
    float* __restrict__ out)
{
    __shared__ float nd_lds[CPB][NK][8];   // padded rows (32B) -> 16 KB
    __shared__ int   adj_lds[CPB][NH];
    __shared__ float d_lds[CPB][NH];
    __shared__ float m_lds[CPB][NH];

    const int t = threadIdx.x;
    const int base = blockIdx.x * CPB;

    // ---- distances: 32 cells x 7 neighbors = 224 tasks ----
    if (t < CPB * NH) {
        const int cl = t / NH;
        const int h  = t % NH;
        const int n  = base + cl;
        const int a  = adjc[n * NH + h];
        const int m  = nh_mask[n * NH + h];
        adj_lds[cl][h] = a;
        const float lat_c = coords[n];
        const float lon_c = coords[N_CELLS + n];
        const float lat_n = coords[a];
        const float lon_n = coords[N_CELLS + a];
        float cosd = sinf(lat_c) * sinf(lat_n) +
                     cosf(lat_c) * cosf(lat_n) * cosf(lon_n - lon_c);
        cosd = fminf(fmaxf(cosd, -1.0f + 1e-7f), 1.0f - 1e-7f);
        d_lds[cl][h] = acosf(cosd);
        m_lds[cl][h] = (float)m;
    }

    // ---- per-lane B fragments from packed global (L2-hot, coalesced) ----
    const int lane = t & 63;
    const int wv   = t >> 6;
    const int col  = lane & 15;
    const int grp  = lane >> 4;

    bf16x8 bfrag[8];
    #pragma unroll
    for (int st = 0; st < 8; ++st)
        bfrag[st] = ((const bf16x8*)wf)[(st * 4 + grp) * 16 + col];
    const float bias = b_out[col];

    __syncthreads();

    // ---- lane roles for main phase ----
    const int cl_in_pair = (lane & 15) >> 3;
    const int bv = lane & 7;
    const int b  = bv >> 2;
    const int v  = bv & 3;
    const int e0 = (grp & 1) * 8;
    const int kos_off = grp >> 1;

    bf16x8 xrA[NH], xrB[NH];

#define LOADXR(XR, PIDX)                                                        \
    {                                                                           \
        const int cl_ = (wv << 3) + ((PIDX) << 1) + cl_in_pair;                 \
        _Pragma("unroll")                                                       \
        for (int h = 0; h < NH; ++h) {                                          \
            const int a = adj_lds[cl_][h];                                      \
            XR[h] = *(const bf16x8*)(xp +                                       \
                ((((size_t)b * N_CELLS + a) * NV + v) << 4) + e0);              \
        }                                                                       \
    }

    // prefetch pairs 0,1 NOW — latency hides under the nd phase below
    LOADXR(xrA, 0)
    LOADXR(xrB, 1)

    // ---- nd weights: 32 cells x 16 (o,s) = 512 tasks, 2/thread ----
    #pragma unroll
    for (int it = 0; it < 2; ++it) {
        const int task = it * THREADS + t;
        const int cl = task >> 4;
        const int k  = task & 15;          // k = o*N_SIG + s
        const int o  = k >> 2;
        const int s  = k & 3;
        const float off     = dist_offsets[o];
        const float inv_sig = 1.0f / sigma[s];
        float raw[NH];
        float sum = 0.0f;
        #pragma unroll
        for (int h = 0; h < NH; ++h) {
            const float df = (d_lds[cl][h] - off) * inv_sig;
            const float e  = __expf(-0.5f * df * df) * m_lds[cl][h];
            raw[h] = e;
            sum += e;
        }
        const float inv = 1.0f / (sum + 1e-8f);
        #pragma unroll
        for (int h = 0; h < NH; ++h)
            nd_lds[cl][k][h] = raw[h] * inv;
        nd_lds[cl][k][7] = 0.0f;           // pad slot
    }
    __syncthreads();

#define COMPUTE(XR, PIDX)                                                       \
    {                                                                           \
        const int c0_ = (wv << 3) + ((PIDX) << 1);                              \
        const int cl_ = c0_ + cl_in_pair;                                       \
        f32x4 acc = {0.f, 0.f, 0.f, 0.f};                                       \
        _Pragma("unroll")                                                       \
        for (int st = 0; st < 8; ++st) {                                        \
            const int k2 = st * 2 + kos_off;                                    \
            const float4 n0 = *(const float4*)&nd_lds[cl_][k2][0];              \
            const float4 n1 = *(const float4*)&nd_lds[cl_][k2][4];              \
            const float nds[NH] = {n0.x, n0.y, n0.z, n0.w, n1.x, n1.y, n1.z};   \
            bf16x8 aa;                                                          \
            _Pragma("unroll")                                                   \
            for (int j = 0; j < 8; ++j) {                                       \
                float s = 0.0f;                                                 \
                _Pragma("unroll")                                               \
                for (int h = 0; h < NH; ++h) s += nds[h] * b2f(XR[h][j]);       \
                aa[j] = f2bfs(s);                                               \
            }                                                                   \
            acc = __builtin_amdgcn_mfma_f32_16x16x32_bf16(aa, bfrag[st], acc, 0, 0, 0); \
        }                                                                       \
        _Pragma("unroll")                                                       \
        for (int r = 0; r < 4; ++r) {                                           \
            const int rr  = grp * 4 + r;                                        \
            const int cs  = rr >> 3;                                            \
            const int bvs = rr & 7;                                             \
            const int bs  = bvs >> 2;                                           \
            const int vs  = bvs & 3;                                            \
            const int cell = base + c0_ + cs;                                   \
            out[((((size_t)bs * N_CELLS + cell) * NV + vs) << 4) + col] = acc[r] + bias; \
        }                                                                       \
    }

    COMPUTE(xrA, 0)
    LOADXR(xrA, 2)
    COMPUTE(xrB, 1)
    LOADXR(xrB, 3)
    COMPUTE(xrA, 2)
    COMPUTE(xrB, 3)

#undef LOADXR
#undef COMPUTE
}

extern "C" void kernel_launch(void* const* d_in, const int* in_sizes, int n_in,
                              void* d_out, int out_size, void* d_ws, size_t ws_size,
                              hipStream_t stream) {
    const float* x            = (const float*)d_in[0];
    const float* coords       = (const float*)d_in[1];
    const float* sigma        = (const float*)d_in[2];
    const float* dist_offsets = (const float*)d_in[3];
    const float* W            = (const float*)d_in[4];
    const float* b_out        = (const float*)d_in[5];
    const int*   adjc         = (const int*)d_in[6];
    const int*   nh_mask      = (const int*)d_in[7];
    float* out = (float*)d_out;

    short* wf = (short*)d_ws;                    // 8 KB packed W fragments
    short* xp = (short*)d_ws + 4096;             // bf16 x copy (16.7 MB)

    const int x_elems  = in_sizes[0];            // 8388608
    const int cv_blocks = x_elems / (256 * 8);   // 4096

    setup_kernel<<<cv_blocks, 256, 0, stream>>>(x, W, wf, xp);
    dim3 grid(N_CELLS / CPB);
    mge_kernel<<<grid, THREADS, 0, stream>>>(xp, coords, sigma, dist_offsets, wf,
                                             b_out, adjc, nh_mask, out);
}